// Round 1
// baseline (1716.740 us; speedup 1.0000x reference)
//
#include <hip/hip_runtime.h>
#include <hip/hip_bf16.h>

#define TTOK 4096   // B*S tokens
#define DIM  2048   // hidden dim
#define FF   4096   // expert ffn dim
#define NE   8      // experts
// top-k = 2

typedef __attribute__((ext_vector_type(4))) float  f32x4;
typedef __attribute__((ext_vector_type(8))) short  s16x8;
typedef __attribute__((ext_vector_type(8))) unsigned short u16x8;

__device__ __forceinline__ unsigned short f2bf(float f) {
  union { __hip_bfloat16 h; unsigned short u; } cv;
  cv.h = __float2bfloat16(f);
  return cv.u;
}

// ---------------- router: logits -> softmax -> top2 -> counts ----------------
__global__ void router_kernel(const float* __restrict__ x,
                              const float* __restrict__ gate_w,
                              int* __restrict__ tope, float* __restrict__ topw,
                              int* __restrict__ counts) {
  const int t = blockIdx.x;
  const int tid = threadIdx.x;
  const float* xr = x + (size_t)t * DIM;
  float p[NE];
#pragma unroll
  for (int e = 0; e < NE; ++e) p[e] = 0.f;
  for (int d = tid; d < DIM; d += 256) {
    float xv = xr[d];
#pragma unroll
    for (int e = 0; e < NE; ++e) p[e] += xv * gate_w[e * DIM + d];
  }
#pragma unroll
  for (int off = 32; off > 0; off >>= 1) {
#pragma unroll
    for (int e = 0; e < NE; ++e) p[e] += __shfl_down(p[e], off);
  }
  __shared__ float red[4][NE];
  const int wid = tid >> 6, lane = tid & 63;
  if (lane == 0) {
#pragma unroll
    for (int e = 0; e < NE; ++e) red[wid][e] = p[e];
  }
  __syncthreads();
  if (tid == 0) {
    float l[NE];
#pragma unroll
    for (int e = 0; e < NE; ++e) l[e] = red[0][e] + red[1][e] + red[2][e] + red[3][e];
    float mx = l[0];
#pragma unroll
    for (int e = 1; e < NE; ++e) mx = fmaxf(mx, l[e]);
    float pr[NE]; float sum = 0.f;
#pragma unroll
    for (int e = 0; e < NE; ++e) { pr[e] = __expf(l[e] - mx); sum += pr[e]; }
    float inv = 1.f / sum;
#pragma unroll
    for (int e = 0; e < NE; ++e) pr[e] *= inv;
    int i0 = 0; float p0 = pr[0];
#pragma unroll
    for (int e = 1; e < NE; ++e) if (pr[e] > p0) { p0 = pr[e]; i0 = e; }
    int i1 = -1; float p1 = -1.f;
#pragma unroll
    for (int e = 0; e < NE; ++e) if (e != i0 && pr[e] > p1) { p1 = pr[e]; i1 = e; }
    float wsum = p0 + p1;
    tope[t * 2 + 0] = i0; topw[t * 2 + 0] = p0 / wsum;
    tope[t * 2 + 1] = i1; topw[t * 2 + 1] = p1 / wsum;
    atomicAdd(&counts[i0], 1);
    atomicAdd(&counts[i1], 1);
  }
}

__global__ void prefix_kernel(const int* __restrict__ counts, int* __restrict__ basep) {
  if (threadIdx.x == 0 && blockIdx.x == 0) {
    int acc = 0;
    for (int e = 0; e < NE; ++e) { basep[e] = acc; acc += counts[e]; }
  }
}

__global__ void fill_kernel(const int* __restrict__ tope, const float* __restrict__ topw,
                            const int* __restrict__ basep, int* __restrict__ fillp,
                            int* __restrict__ rowtok, float* __restrict__ roww) {
  int t = blockIdx.x * blockDim.x + threadIdx.x;
  if (t >= TTOK) return;
#pragma unroll
  for (int s = 0; s < 2; ++s) {
    int e = tope[t * 2 + s];
    int r = basep[e] + atomicAdd(&fillp[e], 1);
    rowtok[r] = t;
    roww[r] = topw[t * 2 + s];
  }
}

// ---------------- GEMM1: H = silu(Xe @ w1^T) * (Xe @ w3^T)  (bf16 out) ------
__global__ __launch_bounds__(256) void gemm1_kernel(
    const float* __restrict__ x, const float* __restrict__ w1,
    const float* __restrict__ w3, const int* __restrict__ rowtok,
    const int* __restrict__ counts, const int* __restrict__ basep,
    unsigned short* __restrict__ H) {
  const int e = blockIdx.z;
  const int cnt = counts[e];
  const int m0 = blockIdx.y * 128;
  if (m0 >= cnt) return;
  const int n0 = blockIdx.x * 128;
  const int base_e = basep[e];

  __shared__ unsigned short As[128 * 32];
  __shared__ unsigned short B1s[128 * 32];
  __shared__ unsigned short B3s[128 * 32];

  const int tid = threadIdx.x;
  const int row = tid >> 1;   // 0..127
  const int seg = tid & 1;    // two 16-float segments per 32-wide k-slice

  const int arow = m0 + row;
  const bool aok = arow < cnt;
  const float* aptr = nullptr;
  if (aok) {
    int tok = rowtok[base_e + arow];
    aptr = x + (size_t)tok * DIM + seg * 16;
  }
  const float* b1ptr = w1 + ((size_t)e * FF + n0 + row) * DIM + seg * 16;
  const float* b3ptr = w3 + ((size_t)e * FF + n0 + row) * DIM + seg * 16;

  const int lane = tid & 63;
  const int wid = tid >> 6;
  const int wr = wid >> 1, wc = wid & 1;
  const int frow = lane & 15;
  const int fk = (lane >> 4) * 8;
  const int lds_off = row * 32 + seg * 16;

  f32x4 acc1[4][4], acc3[4][4];
#pragma unroll
  for (int m = 0; m < 4; ++m)
#pragma unroll
    for (int n = 0; n < 4; ++n) { acc1[m][n] = (f32x4)0.f; acc3[m][n] = (f32x4)0.f; }

  for (int k0 = 0; k0 < DIM; k0 += 32) {
    __syncthreads();
    // stage A (gathered x rows, f32 -> bf16)
    {
      u16x8 lo = (u16x8)0, hi = (u16x8)0;
      if (aok) {
        f32x4 v0 = *(const f32x4*)(aptr + k0);
        f32x4 v1 = *(const f32x4*)(aptr + k0 + 4);
        f32x4 v2 = *(const f32x4*)(aptr + k0 + 8);
        f32x4 v3 = *(const f32x4*)(aptr + k0 + 12);
#pragma unroll
        for (int j = 0; j < 4; ++j) {
          lo[j] = f2bf(v0[j]); lo[j + 4] = f2bf(v1[j]);
          hi[j] = f2bf(v2[j]); hi[j + 4] = f2bf(v3[j]);
        }
      }
      *(u16x8*)&As[lds_off] = lo;
      *(u16x8*)&As[lds_off + 8] = hi;
    }
    // stage B1
    {
      u16x8 lo, hi;
      f32x4 v0 = *(const f32x4*)(b1ptr + k0);
      f32x4 v1 = *(const f32x4*)(b1ptr + k0 + 4);
      f32x4 v2 = *(const f32x4*)(b1ptr + k0 + 8);
      f32x4 v3 = *(const f32x4*)(b1ptr + k0 + 12);
#pragma unroll
      for (int j = 0; j < 4; ++j) {
        lo[j] = f2bf(v0[j]); lo[j + 4] = f2bf(v1[j]);
        hi[j] = f2bf(v2[j]); hi[j + 4] = f2bf(v3[j]);
      }
      *(u16x8*)&B1s[lds_off] = lo;
      *(u16x8*)&B1s[lds_off + 8] = hi;
    }
    // stage B3
    {
      u16x8 lo, hi;
      f32x4 v0 = *(const f32x4*)(b3ptr + k0);
      f32x4 v1 = *(const f32x4*)(b3ptr + k0 + 4);
      f32x4 v2 = *(const f32x4*)(b3ptr + k0 + 8);
      f32x4 v3 = *(const f32x4*)(b3ptr + k0 + 12);
#pragma unroll
      for (int j = 0; j < 4; ++j) {
        lo[j] = f2bf(v0[j]); lo[j + 4] = f2bf(v1[j]);
        hi[j] = f2bf(v2[j]); hi[j + 4] = f2bf(v3[j]);
      }
      *(u16x8*)&B3s[lds_off] = lo;
      *(u16x8*)&B3s[lds_off + 8] = hi;
    }
    __syncthreads();

    s16x8 a[4], b1f[4], b3f[4];
#pragma unroll
    for (int m = 0; m < 4; ++m)
      a[m] = *(const s16x8*)&As[(wr * 64 + m * 16 + frow) * 32 + fk];
#pragma unroll
    for (int n = 0; n < 4; ++n) {
      b1f[n] = *(const s16x8*)&B1s[(wc * 64 + n * 16 + frow) * 32 + fk];
      b3f[n] = *(const s16x8*)&B3s[(wc * 64 + n * 16 + frow) * 32 + fk];
    }
#pragma unroll
    for (int m = 0; m < 4; ++m)
#pragma unroll
      for (int n = 0; n < 4; ++n) {
        acc1[m][n] = __builtin_amdgcn_mfma_f32_16x16x32_bf16(a[m], b1f[n], acc1[m][n], 0, 0, 0);
        acc3[m][n] = __builtin_amdgcn_mfma_f32_16x16x32_bf16(a[m], b3f[n], acc3[m][n], 0, 0, 0);
      }
  }

  // epilogue: silu(c1)*c3 -> H[base_e + grow][col] (bf16)
#pragma unroll
  for (int m = 0; m < 4; ++m) {
#pragma unroll
    for (int n = 0; n < 4; ++n) {
      f32x4 c1 = acc1[m][n], c3 = acc3[m][n];
      int col = n0 + wc * 64 + n * 16 + (lane & 15);
#pragma unroll
      for (int j = 0; j < 4; ++j) {
        int rtile = wr * 64 + m * 16 + (lane >> 4) * 4 + j;
        int grow = m0 + rtile;
        if (grow < cnt) {
          float s = c1[j];
          float hval = (s / (1.f + __expf(-s))) * c3[j];
          H[(size_t)(base_e + grow) * FF + col] = f2bf(hval);
        }
      }
    }
  }
}

// ---------------- GEMM2: y += roww * (H @ w2^T), scatter-add ----------------
__global__ __launch_bounds__(256) void gemm2_kernel(
    const unsigned short* __restrict__ H, const float* __restrict__ w2,
    const int* __restrict__ rowtok, const float* __restrict__ roww,
    const int* __restrict__ counts, const int* __restrict__ basep,
    float* __restrict__ y) {
  const int e = blockIdx.z;
  const int cnt = counts[e];
  const int m0 = blockIdx.y * 128;
  if (m0 >= cnt) return;
  const int n0 = blockIdx.x * 128;   // over DIM
  const int base_e = basep[e];

  __shared__ unsigned short As[128 * 32];
  __shared__ unsigned short Bs[128 * 32];

  const int tid = threadIdx.x;
  const int row = tid >> 1;
  const int seg = tid & 1;

  const int arow = m0 + row;
  const bool aok = arow < cnt;
  const unsigned short* aptr = nullptr;
  if (aok) aptr = H + (size_t)(base_e + arow) * FF + seg * 16;
  const float* bptr = w2 + ((size_t)e * DIM + n0 + row) * FF + seg * 16;

  const int lane = tid & 63;
  const int wid = tid >> 6;
  const int wr = wid >> 1, wc = wid & 1;
  const int frow = lane & 15;
  const int fk = (lane >> 4) * 8;
  const int lds_off = row * 32 + seg * 16;

  f32x4 acc[4][4];
#pragma unroll
  for (int m = 0; m < 4; ++m)
#pragma unroll
    for (int n = 0; n < 4; ++n) acc[m][n] = (f32x4)0.f;

  for (int k0 = 0; k0 < FF; k0 += 32) {
    __syncthreads();
    // stage A (H rows, already bf16)
    {
      u16x8 lo = (u16x8)0, hi = (u16x8)0;
      if (aok) {
        lo = *(const u16x8*)(aptr + k0);
        hi = *(const u16x8*)(aptr + k0 + 8);
      }
      *(u16x8*)&As[lds_off] = lo;
      *(u16x8*)&As[lds_off + 8] = hi;
    }
    // stage B (w2 f32 -> bf16)
    {
      u16x8 lo, hi;
      f32x4 v0 = *(const f32x4*)(bptr + k0);
      f32x4 v1 = *(const f32x4*)(bptr + k0 + 4);
      f32x4 v2 = *(const f32x4*)(bptr + k0 + 8);
      f32x4 v3 = *(const f32x4*)(bptr + k0 + 12);
#pragma unroll
      for (int j = 0; j < 4; ++j) {
        lo[j] = f2bf(v0[j]); lo[j + 4] = f2bf(v1[j]);
        hi[j] = f2bf(v2[j]); hi[j + 4] = f2bf(v3[j]);
      }
      *(u16x8*)&Bs[lds_off] = lo;
      *(u16x8*)&Bs[lds_off + 8] = hi;
    }
    __syncthreads();

    s16x8 a[4], b[4];
#pragma unroll
    for (int m = 0; m < 4; ++m)
      a[m] = *(const s16x8*)&As[(wr * 64 + m * 16 + frow) * 32 + fk];
#pragma unroll
    for (int n = 0; n < 4; ++n)
      b[n] = *(const s16x8*)&Bs[(wc * 64 + n * 16 + frow) * 32 + fk];
#pragma unroll
    for (int m = 0; m < 4; ++m)
#pragma unroll
      for (int n = 0; n < 4; ++n)
        acc[m][n] = __builtin_amdgcn_mfma_f32_16x16x32_bf16(a[m], b[n], acc[m][n], 0, 0, 0);
  }

#pragma unroll
  for (int m = 0; m < 4; ++m) {
#pragma unroll
    for (int n = 0; n < 4; ++n) {
      int col = n0 + wc * 64 + n * 16 + (lane & 15);
#pragma unroll
      for (int j = 0; j < 4; ++j) {
        int rtile = wr * 64 + m * 16 + (lane >> 4) * 4 + j;
        int grow = m0 + rtile;
        if (grow < cnt) {
          int idx = base_e + grow;
          float wrow = roww[idx];
          int tok = rowtok[idx];
          atomicAdd(&y[(size_t)tok * DIM + col], acc[m][n][j] * wrow);
        }
      }
    }
  }
}

extern "C" void kernel_launch(void* const* d_in, const int* in_sizes, int n_in,
                              void* d_out, int out_size, void* d_ws, size_t ws_size,
                              hipStream_t stream) {
  const float* x      = (const float*)d_in[0];
  const float* gate_w = (const float*)d_in[1];
  const float* w1     = (const float*)d_in[2];
  const float* w2     = (const float*)d_in[3];
  const float* w3     = (const float*)d_in[4];
  float* y = (float*)d_out;

  char* ws = (char*)d_ws;
  int*   tope   = (int*)(ws + 0);                 // 4096*2 ints
  float* topw   = (float*)(ws + (32 << 10));      // 4096*2 floats
  int*   rowtok = (int*)(ws + (64 << 10));        // 8192 ints
  float* roww   = (float*)(ws + (96 << 10));      // 8192 floats
  int*   counts = (int*)(ws + (128 << 10));       // 8 ints
  int*   basep  = counts + 32;                    // 8 ints
  int*   fillp  = counts + 64;                    // 8 ints
  unsigned short* H = (unsigned short*)(ws + (1 << 20));  // 8192*4096 bf16 = 64 MB

  hipMemsetAsync(y, 0, (size_t)TTOK * DIM * sizeof(float), stream);
  hipMemsetAsync(counts, 0, 512, stream);

  router_kernel<<<TTOK, 256, 0, stream>>>(x, gate_w, tope, topw, counts);
  prefix_kernel<<<1, 64, 0, stream>>>(counts, basep);
  fill_kernel<<<TTOK / 256, 256, 0, stream>>>(tope, topw, basep, fillp, rowtok, roww);
  gemm1_kernel<<<dim3(FF / 128, TTOK / 128, NE), 256, 0, stream>>>(x, w1, w3, rowtok, counts, basep, H);
  gemm2_kernel<<<dim3(DIM / 128, TTOK / 128, NE), 256, 0, stream>>>(H, w2, rowtok, roww, counts, basep, y);
}

// Round 2
// 1271.938 us; speedup vs baseline: 1.3497x; 1.3497x over previous
//
#include <hip/hip_runtime.h>
#include <hip/hip_bf16.h>

#define TTOK 4096   // B*S tokens
#define DIM  2048   // hidden dim
#define FF   4096   // expert ffn dim
#define NE   8      // experts
#define TROWS 8192  // TTOK * top_k routed rows

typedef __attribute__((ext_vector_type(4))) float  f32x4;
typedef __attribute__((ext_vector_type(8))) short  s16x8;
typedef __attribute__((ext_vector_type(8))) unsigned short u16x8;

__device__ __forceinline__ unsigned short f2bf(float f) {
  union { __hip_bfloat16 h; unsigned short u; } cv;
  cv.h = __float2bfloat16(f);
  return cv.u;
}

// async global->LDS, 16B per lane; LDS dest must be wave-uniform base.
__device__ __forceinline__ void gl_lds16(const void* g, void* s) {
  __builtin_amdgcn_global_load_lds(
      (__attribute__((address_space(1))) void*)(g),
      (__attribute__((address_space(3))) void*)(s), 16, 0, 0);
}

// ---------------- f32 -> bf16 bulk convert (8 elems/thread) -----------------
__global__ __launch_bounds__(256) void cvt_kernel(const float* __restrict__ s,
                                                  unsigned short* __restrict__ d, int n8) {
  int i = blockIdx.x * 256 + threadIdx.x;
  if (i >= n8) return;
  f32x4 v0 = *(const f32x4*)(s + (size_t)i * 8);
  f32x4 v1 = *(const f32x4*)(s + (size_t)i * 8 + 4);
  u16x8 o;
#pragma unroll
  for (int j = 0; j < 4; ++j) { o[j] = f2bf(v0[j]); o[j + 4] = f2bf(v1[j]); }
  *(u16x8*)(d + (size_t)i * 8) = o;
}

// ---------------- router: logits -> softmax -> top2 -> counts ----------------
__global__ void router_kernel(const float* __restrict__ x,
                              const float* __restrict__ gate_w,
                              int* __restrict__ tope, float* __restrict__ topw,
                              int* __restrict__ counts) {
  const int t = blockIdx.x;
  const int tid = threadIdx.x;
  const float* xr = x + (size_t)t * DIM;
  float p[NE];
#pragma unroll
  for (int e = 0; e < NE; ++e) p[e] = 0.f;
  for (int d = tid; d < DIM; d += 256) {
    float xv = xr[d];
#pragma unroll
    for (int e = 0; e < NE; ++e) p[e] += xv * gate_w[e * DIM + d];
  }
#pragma unroll
  for (int off = 32; off > 0; off >>= 1) {
#pragma unroll
    for (int e = 0; e < NE; ++e) p[e] += __shfl_down(p[e], off);
  }
  __shared__ float red[4][NE];
  const int wid = tid >> 6, lane = tid & 63;
  if (lane == 0) {
#pragma unroll
    for (int e = 0; e < NE; ++e) red[wid][e] = p[e];
  }
  __syncthreads();
  if (tid == 0) {
    float l[NE];
#pragma unroll
    for (int e = 0; e < NE; ++e) l[e] = red[0][e] + red[1][e] + red[2][e] + red[3][e];
    float mx = l[0];
#pragma unroll
    for (int e = 1; e < NE; ++e) mx = fmaxf(mx, l[e]);
    float pr[NE]; float sum = 0.f;
#pragma unroll
    for (int e = 0; e < NE; ++e) { pr[e] = __expf(l[e] - mx); sum += pr[e]; }
    float inv = 1.f / sum;
#pragma unroll
    for (int e = 0; e < NE; ++e) pr[e] *= inv;
    int i0 = 0; float p0 = pr[0];
#pragma unroll
    for (int e = 1; e < NE; ++e) if (pr[e] > p0) { p0 = pr[e]; i0 = e; }
    int i1 = -1; float p1 = -1.f;
#pragma unroll
    for (int e = 0; e < NE; ++e) if (e != i0 && pr[e] > p1) { p1 = pr[e]; i1 = e; }
    float wsum = p0 + p1;
    tope[t * 2 + 0] = i0; topw[t * 2 + 0] = p0 / wsum;
    tope[t * 2 + 1] = i1; topw[t * 2 + 1] = p1 / wsum;
    atomicAdd(&counts[i0], 1);
    atomicAdd(&counts[i1], 1);
  }
}

__global__ void prefix_kernel(const int* __restrict__ counts, int* __restrict__ basep) {
  if (threadIdx.x == 0 && blockIdx.x == 0) {
    int acc = 0;
    for (int e = 0; e < NE; ++e) { basep[e] = acc; acc += counts[e]; }
  }
}

__global__ void fill_kernel(const int* __restrict__ tope, const float* __restrict__ topw,
                            const int* __restrict__ basep, int* __restrict__ fillp,
                            int* __restrict__ rowtok, float* __restrict__ roww,
                            int* __restrict__ rowof) {
  int t = blockIdx.x * blockDim.x + threadIdx.x;
  if (t >= TTOK) return;
#pragma unroll
  for (int s = 0; s < 2; ++s) {
    int e = tope[t * 2 + s];
    int r = basep[e] + atomicAdd(&fillp[e], 1);
    rowtok[r] = t;
    roww[r] = topw[t * 2 + s];
    rowof[t * 2 + s] = r;
  }
}

// ========================= TIER A (bf16 weights, global_load_lds) ============
// GEMM1: H = silu(Xe @ w1^T) * (Xe @ w3^T)
__global__ __launch_bounds__(256) void gemm1_a(
    const unsigned short* __restrict__ xb, const unsigned short* __restrict__ w1b,
    const unsigned short* __restrict__ w3b, const int* __restrict__ rowtok,
    const int* __restrict__ counts, const int* __restrict__ basep,
    unsigned short* __restrict__ H) {
  const int e = blockIdx.z;
  const int cnt = counts[e];
  const int m0 = blockIdx.y * 128;
  if (m0 >= cnt) return;
  const int n0 = blockIdx.x * 128;
  const int base_e = basep[e];

  __shared__ unsigned short As[128 * 32];
  __shared__ unsigned short B1s[128 * 32];
  __shared__ unsigned short B3s[128 * 32];

  const int tid = threadIdx.x;
  const int lane = tid & 63;
  const int w = tid >> 6;
  const int lr = lane >> 2;          // row within 16-row stripe
  const int lc = (lane & 3) * 8;     // element col within 32-wide K slice

  // Per-lane global sources (k-invariant bases)
  const unsigned short *aS0, *aS1, *b1S0, *b1S1, *b3S0, *b3S1;
  {
    int r0 = w * 32 + lr, r1 = r0 + 16;
    int g0 = m0 + r0, g1 = m0 + r1;
    int t0 = (g0 < cnt) ? rowtok[base_e + g0] : 0;
    int t1 = (g1 < cnt) ? rowtok[base_e + g1] : 0;
    aS0 = xb + (size_t)t0 * DIM + lc;
    aS1 = xb + (size_t)t1 * DIM + lc;
    b1S0 = w1b + ((size_t)e * FF + n0 + r0) * DIM + lc;
    b1S1 = w1b + ((size_t)e * FF + n0 + r1) * DIM + lc;
    b3S0 = w3b + ((size_t)e * FF + n0 + r0) * DIM + lc;
    b3S1 = w3b + ((size_t)e * FF + n0 + r1) * DIM + lc;
  }
  // Wave-uniform LDS dests (each issue covers 16 rows x 32 cols = 1KB)
  unsigned short* aD0 = &As[(w * 32) * 32];
  unsigned short* aD1 = &As[(w * 32 + 16) * 32];
  unsigned short* b1D0 = &B1s[(w * 32) * 32];
  unsigned short* b1D1 = &B1s[(w * 32 + 16) * 32];
  unsigned short* b3D0 = &B3s[(w * 32) * 32];
  unsigned short* b3D1 = &B3s[(w * 32 + 16) * 32];

  const int wr = w >> 1, wc = w & 1;
  const int frow = lane & 15;
  const int fk = (lane >> 4) * 8;

  f32x4 acc1[4][4], acc3[4][4];
#pragma unroll
  for (int m = 0; m < 4; ++m)
#pragma unroll
    for (int n = 0; n < 4; ++n) { acc1[m][n] = (f32x4)0.f; acc3[m][n] = (f32x4)0.f; }

  for (int k0 = 0; k0 < DIM; k0 += 32) {
    __syncthreads();                       // prev-step LDS reads done
    gl_lds16(aS0 + k0, aD0);
    gl_lds16(aS1 + k0, aD1);
    gl_lds16(b1S0 + k0, b1D0);
    gl_lds16(b1S1 + k0, b1D1);
    gl_lds16(b3S0 + k0, b3D0);
    gl_lds16(b3S1 + k0, b3D1);
    asm volatile("s_waitcnt vmcnt(0)" ::: "memory");
    __syncthreads();                       // tile staged for everyone

    s16x8 a[4], b1f[4], b3f[4];
#pragma unroll
    for (int m = 0; m < 4; ++m)
      a[m] = *(const s16x8*)&As[(wr * 64 + m * 16 + frow) * 32 + fk];
#pragma unroll
    for (int n = 0; n < 4; ++n) {
      b1f[n] = *(const s16x8*)&B1s[(wc * 64 + n * 16 + frow) * 32 + fk];
      b3f[n] = *(const s16x8*)&B3s[(wc * 64 + n * 16 + frow) * 32 + fk];
    }
#pragma unroll
    for (int m = 0; m < 4; ++m)
#pragma unroll
      for (int n = 0; n < 4; ++n) {
        acc1[m][n] = __builtin_amdgcn_mfma_f32_16x16x32_bf16(a[m], b1f[n], acc1[m][n], 0, 0, 0);
        acc3[m][n] = __builtin_amdgcn_mfma_f32_16x16x32_bf16(a[m], b3f[n], acc3[m][n], 0, 0, 0);
      }
  }

#pragma unroll
  for (int m = 0; m < 4; ++m) {
#pragma unroll
    for (int n = 0; n < 4; ++n) {
      f32x4 c1 = acc1[m][n], c3 = acc3[m][n];
      int col = n0 + wc * 64 + n * 16 + frow;
#pragma unroll
      for (int j = 0; j < 4; ++j) {
        int rtile = wr * 64 + m * 16 + (lane >> 4) * 4 + j;
        int grow = m0 + rtile;
        if (grow < cnt) {
          float s = c1[j];
          float hval = (s / (1.f + __expf(-s))) * c3[j];
          H[(size_t)(base_e + grow) * FF + col] = f2bf(hval);
        }
      }
    }
  }
}

// GEMM2: R[r,:] = roww[r] * (H[r,:] @ w2^T)
__global__ __launch_bounds__(256) void gemm2_a(
    const unsigned short* __restrict__ H, const unsigned short* __restrict__ w2b,
    const float* __restrict__ roww, const int* __restrict__ counts,
    const int* __restrict__ basep, float* __restrict__ R) {
  const int e = blockIdx.z;
  const int cnt = counts[e];
  const int m0 = blockIdx.y * 128;
  if (m0 >= cnt) return;
  const int n0 = blockIdx.x * 128;
  const int base_e = basep[e];

  __shared__ unsigned short As[128 * 32];
  __shared__ unsigned short Bs[128 * 32];

  const int tid = threadIdx.x;
  const int lane = tid & 63;
  const int w = tid >> 6;
  const int lr = lane >> 2;
  const int lc = (lane & 3) * 8;

  const unsigned short *aS0, *aS1, *bS0, *bS1;
  {
    int r0 = w * 32 + lr, r1 = r0 + 16;
    int g0 = base_e + m0 + r0; if (g0 > TROWS - 1) g0 = TROWS - 1;
    int g1 = base_e + m0 + r1; if (g1 > TROWS - 1) g1 = TROWS - 1;
    aS0 = H + (size_t)g0 * FF + lc;
    aS1 = H + (size_t)g1 * FF + lc;
    bS0 = w2b + ((size_t)e * DIM + n0 + r0) * FF + lc;
    bS1 = w2b + ((size_t)e * DIM + n0 + r1) * FF + lc;
  }
  unsigned short* aD0 = &As[(w * 32) * 32];
  unsigned short* aD1 = &As[(w * 32 + 16) * 32];
  unsigned short* bD0 = &Bs[(w * 32) * 32];
  unsigned short* bD1 = &Bs[(w * 32 + 16) * 32];

  const int wr = w >> 1, wc = w & 1;
  const int frow = lane & 15;
  const int fk = (lane >> 4) * 8;

  f32x4 acc[4][4];
#pragma unroll
  for (int m = 0; m < 4; ++m)
#pragma unroll
    for (int n = 0; n < 4; ++n) acc[m][n] = (f32x4)0.f;

  for (int k0 = 0; k0 < FF; k0 += 32) {
    __syncthreads();
    gl_lds16(aS0 + k0, aD0);
    gl_lds16(aS1 + k0, aD1);
    gl_lds16(bS0 + k0, bD0);
    gl_lds16(bS1 + k0, bD1);
    asm volatile("s_waitcnt vmcnt(0)" ::: "memory");
    __syncthreads();

    s16x8 a[4], b[4];
#pragma unroll
    for (int m = 0; m < 4; ++m)
      a[m] = *(const s16x8*)&As[(wr * 64 + m * 16 + frow) * 32 + fk];
#pragma unroll
    for (int n = 0; n < 4; ++n)
      b[n] = *(const s16x8*)&Bs[(wc * 64 + n * 16 + frow) * 32 + fk];
#pragma unroll
    for (int m = 0; m < 4; ++m)
#pragma unroll
      for (int n = 0; n < 4; ++n)
        acc[m][n] = __builtin_amdgcn_mfma_f32_16x16x32_bf16(a[m], b[n], acc[m][n], 0, 0, 0);
  }

#pragma unroll
  for (int m = 0; m < 4; ++m) {
#pragma unroll
    for (int n = 0; n < 4; ++n) {
      int col = n0 + wc * 64 + n * 16 + frow;
#pragma unroll
      for (int j = 0; j < 4; ++j) {
        int rtile = wr * 64 + m * 16 + (lane >> 4) * 4 + j;
        int grow = m0 + rtile;
        if (grow < cnt) {
          int idx = base_e + grow;
          R[(size_t)idx * DIM + col] = acc[m][n][j] * roww[idx];
        }
      }
    }
  }
}

// y[t,:] = R[row0(t),:] + R[row1(t),:]
__global__ __launch_bounds__(256) void combine_kernel(const float* __restrict__ R,
                                                      const int* __restrict__ rowof,
                                                      float* __restrict__ y) {
  int idx = blockIdx.x * 256 + threadIdx.x;   // one f32x4 each, T*D/4 total
  int t = idx >> 9;                           // D/4 = 512
  int d4 = idx & 511;
  int r0 = rowof[t * 2], r1 = rowof[t * 2 + 1];
  f32x4 a = *(const f32x4*)(R + (size_t)r0 * DIM + d4 * 4);
  f32x4 b = *(const f32x4*)(R + (size_t)r1 * DIM + d4 * 4);
  *(f32x4*)(y + (size_t)t * DIM + d4 * 4) = a + b;
}

// ========================= TIER B (fallback: round-0 kernels) ================
__global__ __launch_bounds__(256) void gemm1_b(
    const float* __restrict__ x, const float* __restrict__ w1,
    const float* __restrict__ w3, const int* __restrict__ rowtok,
    const int* __restrict__ counts, const int* __restrict__ basep,
    unsigned short* __restrict__ H) {
  const int e = blockIdx.z;
  const int cnt = counts[e];
  const int m0 = blockIdx.y * 128;
  if (m0 >= cnt) return;
  const int n0 = blockIdx.x * 128;
  const int base_e = basep[e];

  __shared__ unsigned short As[128 * 32];
  __shared__ unsigned short B1s[128 * 32];
  __shared__ unsigned short B3s[128 * 32];

  const int tid = threadIdx.x;
  const int row = tid >> 1;
  const int seg = tid & 1;

  const int arow = m0 + row;
  const bool aok = arow < cnt;
  const float* aptr = nullptr;
  if (aok) {
    int tok = rowtok[base_e + arow];
    aptr = x + (size_t)tok * DIM + seg * 16;
  }
  const float* b1ptr = w1 + ((size_t)e * FF + n0 + row) * DIM + seg * 16;
  const float* b3ptr = w3 + ((size_t)e * FF + n0 + row) * DIM + seg * 16;

  const int lane = tid & 63;
  const int wid = tid >> 6;
  const int wr = wid >> 1, wc = wid & 1;
  const int frow = lane & 15;
  const int fk = (lane >> 4) * 8;
  const int lds_off = row * 32 + seg * 16;

  f32x4 acc1[4][4], acc3[4][4];
#pragma unroll
  for (int m = 0; m < 4; ++m)
#pragma unroll
    for (int n = 0; n < 4; ++n) { acc1[m][n] = (f32x4)0.f; acc3[m][n] = (f32x4)0.f; }

  for (int k0 = 0; k0 < DIM; k0 += 32) {
    __syncthreads();
    {
      u16x8 lo = (u16x8)0, hi = (u16x8)0;
      if (aok) {
        f32x4 v0 = *(const f32x4*)(aptr + k0);
        f32x4 v1 = *(const f32x4*)(aptr + k0 + 4);
        f32x4 v2 = *(const f32x4*)(aptr + k0 + 8);
        f32x4 v3 = *(const f32x4*)(aptr + k0 + 12);
#pragma unroll
        for (int j = 0; j < 4; ++j) {
          lo[j] = f2bf(v0[j]); lo[j + 4] = f2bf(v1[j]);
          hi[j] = f2bf(v2[j]); hi[j + 4] = f2bf(v3[j]);
        }
      }
      *(u16x8*)&As[lds_off] = lo;
      *(u16x8*)&As[lds_off + 8] = hi;
    }
    {
      u16x8 lo, hi;
      f32x4 v0 = *(const f32x4*)(b1ptr + k0);
      f32x4 v1 = *(const f32x4*)(b1ptr + k0 + 4);
      f32x4 v2 = *(const f32x4*)(b1ptr + k0 + 8);
      f32x4 v3 = *(const f32x4*)(b1ptr + k0 + 12);
#pragma unroll
      for (int j = 0; j < 4; ++j) {
        lo[j] = f2bf(v0[j]); lo[j + 4] = f2bf(v1[j]);
        hi[j] = f2bf(v2[j]); hi[j + 4] = f2bf(v3[j]);
      }
      *(u16x8*)&B1s[lds_off] = lo;
      *(u16x8*)&B1s[lds_off + 8] = hi;
    }
    {
      u16x8 lo, hi;
      f32x4 v0 = *(const f32x4*)(b3ptr + k0);
      f32x4 v1 = *(const f32x4*)(b3ptr + k0 + 4);
      f32x4 v2 = *(const f32x4*)(b3ptr + k0 + 8);
      f32x4 v3 = *(const f32x4*)(b3ptr + k0 + 12);
#pragma unroll
      for (int j = 0; j < 4; ++j) {
        lo[j] = f2bf(v0[j]); lo[j + 4] = f2bf(v1[j]);
        hi[j] = f2bf(v2[j]); hi[j + 4] = f2bf(v3[j]);
      }
      *(u16x8*)&B3s[lds_off] = lo;
      *(u16x8*)&B3s[lds_off + 8] = hi;
    }
    __syncthreads();

    s16x8 a[4], b1f[4], b3f[4];
#pragma unroll
    for (int m = 0; m < 4; ++m)
      a[m] = *(const s16x8*)&As[(wr * 64 + m * 16 + frow) * 32 + fk];
#pragma unroll
    for (int n = 0; n < 4; ++n) {
      b1f[n] = *(const s16x8*)&B1s[(wc * 64 + n * 16 + frow) * 32 + fk];
      b3f[n] = *(const s16x8*)&B3s[(wc * 64 + n * 16 + frow) * 32 + fk];
    }
#pragma unroll
    for (int m = 0; m < 4; ++m)
#pragma unroll
      for (int n = 0; n < 4; ++n) {
        acc1[m][n] = __builtin_amdgcn_mfma_f32_16x16x32_bf16(a[m], b1f[n], acc1[m][n], 0, 0, 0);
        acc3[m][n] = __builtin_amdgcn_mfma_f32_16x16x32_bf16(a[m], b3f[n], acc3[m][n], 0, 0, 0);
      }
  }

#pragma unroll
  for (int m = 0; m < 4; ++m) {
#pragma unroll
    for (int n = 0; n < 4; ++n) {
      f32x4 c1 = acc1[m][n], c3 = acc3[m][n];
      int col = n0 + wc * 64 + n * 16 + frow;
#pragma unroll
      for (int j = 0; j < 4; ++j) {
        int rtile = wr * 64 + m * 16 + (lane >> 4) * 4 + j;
        int grow = m0 + rtile;
        if (grow < cnt) {
          float s = c1[j];
          float hval = (s / (1.f + __expf(-s))) * c3[j];
          H[(size_t)(base_e + grow) * FF + col] = f2bf(hval);
        }
      }
    }
  }
}

__global__ __launch_bounds__(256) void gemm2_b(
    const unsigned short* __restrict__ H, const float* __restrict__ w2,
    const int* __restrict__ rowtok, const float* __restrict__ roww,
    const int* __restrict__ counts, const int* __restrict__ basep,
    float* __restrict__ y) {
  const int e = blockIdx.z;
  const int cnt = counts[e];
  const int m0 = blockIdx.y * 128;
  if (m0 >= cnt) return;
  const int n0 = blockIdx.x * 128;
  const int base_e = basep[e];

  __shared__ unsigned short As[128 * 32];
  __shared__ unsigned short Bs[128 * 32];

  const int tid = threadIdx.x;
  const int row = tid >> 1;
  const int seg = tid & 1;

  const int arow = m0 + row;
  const bool aok = arow < cnt;
  const unsigned short* aptr = nullptr;
  if (aok) aptr = H + (size_t)(base_e + arow) * FF + seg * 16;
  const float* bptr = w2 + ((size_t)e * DIM + n0 + row) * FF + seg * 16;

  const int lane = tid & 63;
  const int wid = tid >> 6;
  const int wr = wid >> 1, wc = wid & 1;
  const int frow = lane & 15;
  const int fk = (lane >> 4) * 8;
  const int lds_off = row * 32 + seg * 16;

  f32x4 acc[4][4];
#pragma unroll
  for (int m = 0; m < 4; ++m)
#pragma unroll
    for (int n = 0; n < 4; ++n) acc[m][n] = (f32x4)0.f;

  for (int k0 = 0; k0 < FF; k0 += 32) {
    __syncthreads();
    {
      u16x8 lo = (u16x8)0, hi = (u16x8)0;
      if (aok) {
        lo = *(const u16x8*)(aptr + k0);
        hi = *(const u16x8*)(aptr + k0 + 8);
      }
      *(u16x8*)&As[lds_off] = lo;
      *(u16x8*)&As[lds_off + 8] = hi;
    }
    {
      u16x8 lo, hi;
      f32x4 v0 = *(const f32x4*)(bptr + k0);
      f32x4 v1 = *(const f32x4*)(bptr + k0 + 4);
      f32x4 v2 = *(const f32x4*)(bptr + k0 + 8);
      f32x4 v3 = *(const f32x4*)(bptr + k0 + 12);
#pragma unroll
      for (int j = 0; j < 4; ++j) {
        lo[j] = f2bf(v0[j]); lo[j + 4] = f2bf(v1[j]);
        hi[j] = f2bf(v2[j]); hi[j + 4] = f2bf(v3[j]);
      }
      *(u16x8*)&Bs[lds_off] = lo;
      *(u16x8*)&Bs[lds_off + 8] = hi;
    }
    __syncthreads();

    s16x8 a[4], b[4];
#pragma unroll
    for (int m = 0; m < 4; ++m)
      a[m] = *(const s16x8*)&As[(wr * 64 + m * 16 + frow) * 32 + fk];
#pragma unroll
    for (int n = 0; n < 4; ++n)
      b[n] = *(const s16x8*)&Bs[(wc * 64 + n * 16 + frow) * 32 + fk];
#pragma unroll
    for (int m = 0; m < 4; ++m)
#pragma unroll
      for (int n = 0; n < 4; ++n)
        acc[m][n] = __builtin_amdgcn_mfma_f32_16x16x32_bf16(a[m], b[n], acc[m][n], 0, 0, 0);
  }

#pragma unroll
  for (int m = 0; m < 4; ++m) {
#pragma unroll
    for (int n = 0; n < 4; ++n) {
      int col = n0 + wc * 64 + n * 16 + frow;
#pragma unroll
      for (int j = 0; j < 4; ++j) {
        int rtile = wr * 64 + m * 16 + (lane >> 4) * 4 + j;
        int grow = m0 + rtile;
        if (grow < cnt) {
          int idx = base_e + grow;
          float wrow = roww[idx];
          int tok = rowtok[idx];
          atomicAdd(&y[(size_t)tok * DIM + col], acc[m][n][j] * wrow);
        }
      }
    }
  }
}

extern "C" void kernel_launch(void* const* d_in, const int* in_sizes, int n_in,
                              void* d_out, int out_size, void* d_ws, size_t ws_size,
                              hipStream_t stream) {
  const float* x      = (const float*)d_in[0];
  const float* gate_w = (const float*)d_in[1];
  const float* w1     = (const float*)d_in[2];
  const float* w2     = (const float*)d_in[3];
  const float* w3     = (const float*)d_in[4];
  float* y = (float*)d_out;

  char* ws = (char*)d_ws;
  const size_t MB = 1ull << 20;
  // control block
  int*   tope   = (int*)(ws);
  float* topw   = (float*)(ws + (32 << 10));
  int*   rowtok = (int*)(ws + (64 << 10));
  float* roww   = (float*)(ws + (96 << 10));
  int*   rowof  = (int*)(ws + (128 << 10));
  int*   counts = (int*)(ws + (160 << 10));
  int*   basep  = counts + 32;
  int*   fillp  = counts + 64;

  const bool tierA = ws_size >= 530 * MB;

  hipMemsetAsync(counts, 0, 512, stream);
  router_kernel<<<TTOK, 256, 0, stream>>>(x, gate_w, tope, topw, counts);
  prefix_kernel<<<1, 64, 0, stream>>>(counts, basep);
  fill_kernel<<<TTOK / 256, 256, 0, stream>>>(tope, topw, basep, fillp, rowtok, roww, rowof);

  if (tierA) {
    unsigned short* xb  = (unsigned short*)(ws + 1 * MB);    // 16 MB
    unsigned short* H   = (unsigned short*)(ws + 17 * MB);   // 64 MB
    float*          R   = (float*)(ws + 81 * MB);            // 64 MB
    unsigned short* w1b = (unsigned short*)(ws + 145 * MB);  // 128 MB
    unsigned short* w3b = (unsigned short*)(ws + 273 * MB);  // 128 MB
    unsigned short* w2b = (unsigned short*)(ws + 401 * MB);  // 128 MB (end 529)

    const int nw8 = NE * FF * DIM / 8;       // 8Mi chunks per weight tensor
    const int nx8 = TTOK * DIM / 8;          // 1Mi chunks
    cvt_kernel<<<nw8 / 256, 256, 0, stream>>>(w1, w1b, nw8);
    cvt_kernel<<<nw8 / 256, 256, 0, stream>>>(w3, w3b, nw8);
    cvt_kernel<<<nw8 / 256, 256, 0, stream>>>(w2, w2b, nw8);
    cvt_kernel<<<nx8 / 256, 256, 0, stream>>>(x, xb, nx8);

    gemm1_a<<<dim3(FF / 128, TTOK / 128, NE), 256, 0, stream>>>(
        xb, w1b, w3b, rowtok, counts, basep, H);
    gemm2_a<<<dim3(DIM / 128, TTOK / 128, NE), 256, 0, stream>>>(
        H, w2b, roww, counts, basep, R);
    combine_kernel<<<TTOK * DIM / 4 / 256, 256, 0, stream>>>(R, rowof, y);
  } else {
    unsigned short* H = (unsigned short*)(ws + 1 * MB);      // 64 MB
    hipMemsetAsync(y, 0, (size_t)TTOK * DIM * sizeof(float), stream);
    gemm1_b<<<dim3(FF / 128, TTOK / 128, NE), 256, 0, stream>>>(
        x, w1, w3, rowtok, counts, basep, H);
    gemm2_b<<<dim3(DIM / 128, TTOK / 128, NE), 256, 0, stream>>>(
        H, w2, rowtok, roww, counts, basep, y);
  }
}

// Round 3
// 1254.173 us; speedup vs baseline: 1.3688x; 1.0142x over previous
//
#include <hip/hip_runtime.h>
#include <hip/hip_bf16.h>

#define TTOK 4096   // B*S tokens
#define DIM  2048   // hidden dim
#define FF   4096   // expert ffn dim
#define NE   8      // experts
#define TROWS 8192  // TTOK * top_k routed rows

typedef __attribute__((ext_vector_type(4))) float  f32x4;
typedef __attribute__((ext_vector_type(8))) short  s16x8;
typedef __attribute__((ext_vector_type(8))) unsigned short u16x8;

__device__ __forceinline__ unsigned short f2bf(float f) {
  union { __hip_bfloat16 h; unsigned short u; } cv;
  cv.h = __float2bfloat16(f);
  return cv.u;
}

// async global->LDS, 16B per lane; LDS dest is wave-uniform base + lane*16B.
__device__ __forceinline__ void gl_lds16(const void* g, void* s) {
  __builtin_amdgcn_global_load_lds(
      (__attribute__((address_space(1))) void*)(g),
      (__attribute__((address_space(3))) void*)(s), 16, 0, 0);
}

// ---------------- f32 -> bf16 bulk convert (8 elems/thread) -----------------
__global__ __launch_bounds__(256) void cvt_kernel(const float* __restrict__ s,
                                                  unsigned short* __restrict__ d, int n8) {
  int i = blockIdx.x * 256 + threadIdx.x;
  if (i >= n8) return;
  f32x4 v0 = *(const f32x4*)(s + (size_t)i * 8);
  f32x4 v1 = *(const f32x4*)(s + (size_t)i * 8 + 4);
  u16x8 o;
#pragma unroll
  for (int j = 0; j < 4; ++j) { o[j] = f2bf(v0[j]); o[j + 4] = f2bf(v1[j]); }
  *(u16x8*)(d + (size_t)i * 8) = o;
}

// ---------------- router: logits -> softmax -> top2 -> counts ----------------
__global__ void router_kernel(const float* __restrict__ x,
                              const float* __restrict__ gate_w,
                              int* __restrict__ tope, float* __restrict__ topw,
                              int* __restrict__ counts) {
  const int t = blockIdx.x;
  const int tid = threadIdx.x;
  const float* xr = x + (size_t)t * DIM;
  float p[NE];
#pragma unroll
  for (int e = 0; e < NE; ++e) p[e] = 0.f;
  for (int d = tid; d < DIM; d += 256) {
    float xv = xr[d];
#pragma unroll
    for (int e = 0; e < NE; ++e) p[e] += xv * gate_w[e * DIM + d];
  }
#pragma unroll
  for (int off = 32; off > 0; off >>= 1) {
#pragma unroll
    for (int e = 0; e < NE; ++e) p[e] += __shfl_down(p[e], off);
  }
  __shared__ float red[4][NE];
  const int wid = tid >> 6, lane = tid & 63;
  if (lane == 0) {
#pragma unroll
    for (int e = 0; e < NE; ++e) red[wid][e] = p[e];
  }
  __syncthreads();
  if (tid == 0) {
    float l[NE];
#pragma unroll
    for (int e = 0; e < NE; ++e) l[e] = red[0][e] + red[1][e] + red[2][e] + red[3][e];
    float mx = l[0];
#pragma unroll
    for (int e = 1; e < NE; ++e) mx = fmaxf(mx, l[e]);
    float pr[NE]; float sum = 0.f;
#pragma unroll
    for (int e = 0; e < NE; ++e) { pr[e] = __expf(l[e] - mx); sum += pr[e]; }
    float inv = 1.f / sum;
#pragma unroll
    for (int e = 0; e < NE; ++e) pr[e] *= inv;
    int i0 = 0; float p0 = pr[0];
#pragma unroll
    for (int e = 1; e < NE; ++e) if (pr[e] > p0) { p0 = pr[e]; i0 = e; }
    int i1 = -1; float p1 = -1.f;
#pragma unroll
    for (int e = 0; e < NE; ++e) if (e != i0 && pr[e] > p1) { p1 = pr[e]; i1 = e; }
    float wsum = p0 + p1;
    tope[t * 2 + 0] = i0; topw[t * 2 + 0] = p0 / wsum;
    tope[t * 2 + 1] = i1; topw[t * 2 + 1] = p1 / wsum;
    atomicAdd(&counts[i0], 1);
    atomicAdd(&counts[i1], 1);
  }
}

__global__ void prefix_kernel(const int* __restrict__ counts, int* __restrict__ basep) {
  if (threadIdx.x == 0 && blockIdx.x == 0) {
    int acc = 0;
    for (int e = 0; e < NE; ++e) { basep[e] = acc; acc += counts[e]; }
  }
}

__global__ void fill_kernel(const int* __restrict__ tope, const float* __restrict__ topw,
                            const int* __restrict__ basep, int* __restrict__ fillp,
                            int* __restrict__ rowtok, float* __restrict__ roww,
                            int* __restrict__ rowof) {
  int t = blockIdx.x * blockDim.x + threadIdx.x;
  if (t >= TTOK) return;
#pragma unroll
  for (int s = 0; s < 2; ++s) {
    int e = tope[t * 2 + s];
    int r = basep[e] + atomicAdd(&fillp[e], 1);
    rowtok[r] = t;
    roww[r] = topw[t * 2 + s];
    rowof[t * 2 + s] = r;
  }
}

// ================= GEMM1: H = silu(Xe @ w1^T) * (Xe @ w3^T), 2-phase =========
__global__ __launch_bounds__(256) void gemm1_a(
    const unsigned short* __restrict__ xb, const unsigned short* __restrict__ w1b,
    const unsigned short* __restrict__ w3b, const int* __restrict__ rowtok,
    const int* __restrict__ counts, const int* __restrict__ basep,
    unsigned short* __restrict__ H) {
  const int e = blockIdx.z;
  const int cnt = counts[e];
  const int m0 = blockIdx.y * 128;
  if (m0 >= cnt) return;
  const int n0 = blockIdx.x * 128;
  const int base_e = basep[e];

  __shared__ unsigned short As[2][128 * 32];
  __shared__ unsigned short B1s[2][128 * 32];
  __shared__ unsigned short B3s[2][128 * 32];

  const int tid = threadIdx.x;
  const int lane = tid & 63;
  const int w = tid >> 6;
  const int lr = lane >> 2;          // row within 16-row stripe
  const int lc = (lane & 3) * 8;     // element col within 32-wide K slice

  const unsigned short *aS0, *aS1, *b1S0, *b1S1, *b3S0, *b3S1;
  {
    int r0 = w * 32 + lr, r1 = r0 + 16;
    int g0 = m0 + r0, g1 = m0 + r1;
    int t0 = (g0 < cnt) ? rowtok[base_e + g0] : 0;
    int t1 = (g1 < cnt) ? rowtok[base_e + g1] : 0;
    aS0 = xb + (size_t)t0 * DIM + lc;
    aS1 = xb + (size_t)t1 * DIM + lc;
    b1S0 = w1b + ((size_t)e * FF + n0 + r0) * DIM + lc;
    b1S1 = w1b + ((size_t)e * FF + n0 + r1) * DIM + lc;
    b3S0 = w3b + ((size_t)e * FF + n0 + r0) * DIM + lc;
    b3S1 = w3b + ((size_t)e * FF + n0 + r1) * DIM + lc;
  }
  const int d0 = (w * 32) * 32;       // wave stripe 0 (16 rows x 32 cols)
  const int d1 = (w * 32 + 16) * 32;  // wave stripe 1

  const int wr = w >> 1, wc = w & 1;
  const int frow = lane & 15;
  const int fk = (lane >> 4) * 8;

  f32x4 acc1[4][4], acc3[4][4];
#pragma unroll
  for (int m = 0; m < 4; ++m)
#pragma unroll
    for (int n = 0; n < 4; ++n) { acc1[m][n] = (f32x4)0.f; acc3[m][n] = (f32x4)0.f; }

#define STAGE1(BUF, K0) do { \
    gl_lds16(aS0 + (K0), &As[BUF][d0]); \
    gl_lds16(aS1 + (K0), &As[BUF][d1]); \
    gl_lds16(b1S0 + (K0), &B1s[BUF][d0]); \
    gl_lds16(b1S1 + (K0), &B1s[BUF][d1]); \
    gl_lds16(b3S0 + (K0), &B3s[BUF][d0]); \
    gl_lds16(b3S1 + (K0), &B3s[BUF][d1]); \
  } while (0)

#define COMPUTE1(BUF) do { \
    s16x8 a[4], b1f[4], b3f[4]; \
    _Pragma("unroll") \
    for (int m = 0; m < 4; ++m) \
      a[m] = *(const s16x8*)&As[BUF][(wr * 64 + m * 16 + frow) * 32 + fk]; \
    _Pragma("unroll") \
    for (int n = 0; n < 4; ++n) { \
      b1f[n] = *(const s16x8*)&B1s[BUF][(wc * 64 + n * 16 + frow) * 32 + fk]; \
      b3f[n] = *(const s16x8*)&B3s[BUF][(wc * 64 + n * 16 + frow) * 32 + fk]; \
    } \
    _Pragma("unroll") \
    for (int m = 0; m < 4; ++m) \
      _Pragma("unroll") \
      for (int n = 0; n < 4; ++n) { \
        acc1[m][n] = __builtin_amdgcn_mfma_f32_16x16x32_bf16(a[m], b1f[n], acc1[m][n], 0, 0, 0); \
        acc3[m][n] = __builtin_amdgcn_mfma_f32_16x16x32_bf16(a[m], b3f[n], acc3[m][n], 0, 0, 0); \
      } \
  } while (0)

  STAGE1(0, 0);
  __syncthreads();                      // tile 0 staged (drains vmcnt)
  // DIM/32 = 64 k-steps, even -> unroll x2 with compile-time buffer index
  for (int k0 = 0; k0 < DIM; k0 += 64) {
    STAGE1(1, k0 + 32);                 // prefetch next while computing cur
    COMPUTE1(0);
    __syncthreads();                    // drains vmcnt+lgkmcnt, barrier
    if (k0 + 64 < DIM) STAGE1(0, k0 + 64);
    COMPUTE1(1);
    __syncthreads();
  }
#undef STAGE1
#undef COMPUTE1

#pragma unroll
  for (int m = 0; m < 4; ++m) {
#pragma unroll
    for (int n = 0; n < 4; ++n) {
      f32x4 c1 = acc1[m][n], c3 = acc3[m][n];
      int col = n0 + wc * 64 + n * 16 + frow;
#pragma unroll
      for (int j = 0; j < 4; ++j) {
        int rtile = wr * 64 + m * 16 + (lane >> 4) * 4 + j;
        int grow = m0 + rtile;
        if (grow < cnt) {
          float s = c1[j];
          float hval = (s / (1.f + __expf(-s))) * c3[j];
          H[(size_t)(base_e + grow) * FF + col] = f2bf(hval);
        }
      }
    }
  }
}

// ================= GEMM2: R[r,:] = roww[r] * (H[r,:] @ w2^T), 2-phase ========
__global__ __launch_bounds__(256) void gemm2_a(
    const unsigned short* __restrict__ H, const unsigned short* __restrict__ w2b,
    const float* __restrict__ roww, const int* __restrict__ counts,
    const int* __restrict__ basep, float* __restrict__ R) {
  const int e = blockIdx.z;
  const int cnt = counts[e];
  const int m0 = blockIdx.y * 128;
  if (m0 >= cnt) return;
  const int n0 = blockIdx.x * 128;
  const int base_e = basep[e];

  __shared__ unsigned short As[2][128 * 32];
  __shared__ unsigned short Bs[2][128 * 32];

  const int tid = threadIdx.x;
  const int lane = tid & 63;
  const int w = tid >> 6;
  const int lr = lane >> 2;
  const int lc = (lane & 3) * 8;

  const unsigned short *aS0, *aS1, *bS0, *bS1;
  {
    int r0 = w * 32 + lr, r1 = r0 + 16;
    int g0 = base_e + m0 + r0; if (g0 > TROWS - 1) g0 = TROWS - 1;
    int g1 = base_e + m0 + r1; if (g1 > TROWS - 1) g1 = TROWS - 1;
    aS0 = H + (size_t)g0 * FF + lc;
    aS1 = H + (size_t)g1 * FF + lc;
    bS0 = w2b + ((size_t)e * DIM + n0 + r0) * FF + lc;
    bS1 = w2b + ((size_t)e * DIM + n0 + r1) * FF + lc;
  }
  const int d0 = (w * 32) * 32;
  const int d1 = (w * 32 + 16) * 32;

  const int wr = w >> 1, wc = w & 1;
  const int frow = lane & 15;
  const int fk = (lane >> 4) * 8;

  f32x4 acc[4][4];
#pragma unroll
  for (int m = 0; m < 4; ++m)
#pragma unroll
    for (int n = 0; n < 4; ++n) acc[m][n] = (f32x4)0.f;

#define STAGE2(BUF, K0) do { \
    gl_lds16(aS0 + (K0), &As[BUF][d0]); \
    gl_lds16(aS1 + (K0), &As[BUF][d1]); \
    gl_lds16(bS0 + (K0), &Bs[BUF][d0]); \
    gl_lds16(bS1 + (K0), &Bs[BUF][d1]); \
  } while (0)

#define COMPUTE2(BUF) do { \
    s16x8 a[4], b[4]; \
    _Pragma("unroll") \
    for (int m = 0; m < 4; ++m) \
      a[m] = *(const s16x8*)&As[BUF][(wr * 64 + m * 16 + frow) * 32 + fk]; \
    _Pragma("unroll") \
    for (int n = 0; n < 4; ++n) \
      b[n] = *(const s16x8*)&Bs[BUF][(wc * 64 + n * 16 + frow) * 32 + fk]; \
    _Pragma("unroll") \
    for (int m = 0; m < 4; ++m) \
      _Pragma("unroll") \
      for (int n = 0; n < 4; ++n) \
        acc[m][n] = __builtin_amdgcn_mfma_f32_16x16x32_bf16(a[m], b[n], acc[m][n], 0, 0, 0); \
  } while (0)

  STAGE2(0, 0);
  __syncthreads();
  // FF/32 = 128 k-steps, even
  for (int k0 = 0; k0 < FF; k0 += 64) {
    STAGE2(1, k0 + 32);
    COMPUTE2(0);
    __syncthreads();
    if (k0 + 64 < FF) STAGE2(0, k0 + 64);
    COMPUTE2(1);
    __syncthreads();
  }
#undef STAGE2
#undef COMPUTE2

#pragma unroll
  for (int m = 0; m < 4; ++m) {
#pragma unroll
    for (int n = 0; n < 4; ++n) {
      int col = n0 + wc * 64 + n * 16 + frow;
#pragma unroll
      for (int j = 0; j < 4; ++j) {
        int rtile = wr * 64 + m * 16 + (lane >> 4) * 4 + j;
        int grow = m0 + rtile;
        if (grow < cnt) {
          int idx = base_e + grow;
          R[(size_t)idx * DIM + col] = acc[m][n][j] * roww[idx];
        }
      }
    }
  }
}

// y[t,:] = R[row0(t),:] + R[row1(t),:]
__global__ __launch_bounds__(256) void combine_kernel(const float* __restrict__ R,
                                                      const int* __restrict__ rowof,
                                                      float* __restrict__ y) {
  int idx = blockIdx.x * 256 + threadIdx.x;   // one f32x4 each, T*D/4 total
  int t = idx >> 9;                           // D/4 = 512
  int d4 = idx & 511;
  int r0 = rowof[t * 2], r1 = rowof[t * 2 + 1];
  f32x4 a = *(const f32x4*)(R + (size_t)r0 * DIM + d4 * 4);
  f32x4 b = *(const f32x4*)(R + (size_t)r1 * DIM + d4 * 4);
  *(f32x4*)(y + (size_t)t * DIM + d4 * 4) = a + b;
}

extern "C" void kernel_launch(void* const* d_in, const int* in_sizes, int n_in,
                              void* d_out, int out_size, void* d_ws, size_t ws_size,
                              hipStream_t stream) {
  const float* x      = (const float*)d_in[0];
  const float* gate_w = (const float*)d_in[1];
  const float* w1     = (const float*)d_in[2];
  const float* w2     = (const float*)d_in[3];
  const float* w3     = (const float*)d_in[4];
  float* y = (float*)d_out;

  char* ws = (char*)d_ws;
  const size_t MB = 1ull << 20;
  // control block
  int*   tope   = (int*)(ws);
  float* topw   = (float*)(ws + (32 << 10));
  int*   rowtok = (int*)(ws + (64 << 10));
  float* roww   = (float*)(ws + (96 << 10));
  int*   rowof  = (int*)(ws + (128 << 10));
  int*   counts = (int*)(ws + (160 << 10));
  int*   basep  = counts + 32;
  int*   fillp  = counts + 64;

  unsigned short* xb  = (unsigned short*)(ws + 1 * MB);    // 16 MB
  unsigned short* H   = (unsigned short*)(ws + 17 * MB);   // 64 MB
  float*          R   = (float*)(ws + 81 * MB);            // 64 MB
  unsigned short* w1b = (unsigned short*)(ws + 145 * MB);  // 128 MB
  unsigned short* w3b = (unsigned short*)(ws + 273 * MB);  // 128 MB
  unsigned short* w2b = (unsigned short*)(ws + 401 * MB);  // 128 MB (end 529)

  hipMemsetAsync(counts, 0, 512, stream);
  router_kernel<<<TTOK, 256, 0, stream>>>(x, gate_w, tope, topw, counts);
  prefix_kernel<<<1, 64, 0, stream>>>(counts, basep);
  fill_kernel<<<TTOK / 256, 256, 0, stream>>>(tope, topw, basep, fillp, rowtok, roww, rowof);

  const int nw8 = NE * FF * DIM / 8;
  const int nx8 = TTOK * DIM / 8;
  cvt_kernel<<<nw8 / 256, 256, 0, stream>>>(w1, w1b, nw8);
  cvt_kernel<<<nw8 / 256, 256, 0, stream>>>(w3, w3b, nw8);
  cvt_kernel<<<nw8 / 256, 256, 0, stream>>>(w2, w2b, nw8);
  cvt_kernel<<<nx8 / 256, 256, 0, stream>>>(x, xb, nx8);

  gemm1_a<<<dim3(FF / 128, TTOK / 128, NE), 256, 0, stream>>>(
      xb, w1b, w3b, rowtok, counts, basep, H);
  gemm2_a<<<dim3(DIM / 128, TTOK / 128, NE), 256, 0, stream>>>(
      H, w2b, roww, counts, basep, R);
  combine_kernel<<<TTOK * DIM / 4 / 256, 256, 0, stream>>>(R, rowof, y);
}

// Round 4
// 1129.192 us; speedup vs baseline: 1.5203x; 1.1107x over previous
//
#include <hip/hip_runtime.h>
#include <hip/hip_bf16.h>

#define TTOK 4096   // B*S tokens
#define DIM  2048   // hidden dim
#define FF   4096   // expert ffn dim
#define NE   8      // experts
#define TROWS 8192  // TTOK * top_k routed rows

#define BM 256
#define BK 64       // K-tile
// 8 waves: 2 in M x 4 in N; per-wave output 128x64

typedef __attribute__((ext_vector_type(4))) float  f32x4;
typedef __attribute__((ext_vector_type(8))) short  s16x8;
typedef __attribute__((ext_vector_type(8))) unsigned short u16x8;

__device__ __forceinline__ unsigned short f2bf(float f) {
  union { __hip_bfloat16 h; unsigned short u; } cv;
  cv.h = __float2bfloat16(f);
  return cv.u;
}
__device__ __forceinline__ float bf2f(unsigned short u) {
  union { unsigned int i; float f; } cv;
  cv.i = ((unsigned int)u) << 16;
  return cv.f;
}

// async global->LDS, 16B per lane; dest = wave-uniform base, HW adds lane*16.
__device__ __forceinline__ void gl_lds16(const void* g, void* s) {
  __builtin_amdgcn_global_load_lds(
      (__attribute__((address_space(1))) void*)(g),
      (__attribute__((address_space(3))) void*)(s), 16, 0, 0);
}

// ---------------- f32 -> bf16 bulk convert (8 elems/thread) -----------------
__global__ __launch_bounds__(256) void cvt_kernel(const float* __restrict__ s,
                                                  unsigned short* __restrict__ d, int n8) {
  int i = blockIdx.x * 256 + threadIdx.x;
  if (i >= n8) return;
  f32x4 v0 = *(const f32x4*)(s + (size_t)i * 8);
  f32x4 v1 = *(const f32x4*)(s + (size_t)i * 8 + 4);
  u16x8 o;
#pragma unroll
  for (int j = 0; j < 4; ++j) { o[j] = f2bf(v0[j]); o[j + 4] = f2bf(v1[j]); }
  *(u16x8*)(d + (size_t)i * 8) = o;
}

// ---------------- router ----------------------------------------------------
__global__ void router_kernel(const float* __restrict__ x,
                              const float* __restrict__ gate_w,
                              int* __restrict__ tope, float* __restrict__ topw,
                              int* __restrict__ counts) {
  const int t = blockIdx.x;
  const int tid = threadIdx.x;
  const float* xr = x + (size_t)t * DIM;
  float p[NE];
#pragma unroll
  for (int e = 0; e < NE; ++e) p[e] = 0.f;
  for (int d = tid; d < DIM; d += 256) {
    float xv = xr[d];
#pragma unroll
    for (int e = 0; e < NE; ++e) p[e] += xv * gate_w[e * DIM + d];
  }
#pragma unroll
  for (int off = 32; off > 0; off >>= 1) {
#pragma unroll
    for (int e = 0; e < NE; ++e) p[e] += __shfl_down(p[e], off);
  }
  __shared__ float red[4][NE];
  const int wid = tid >> 6, lane = tid & 63;
  if (lane == 0) {
#pragma unroll
    for (int e = 0; e < NE; ++e) red[wid][e] = p[e];
  }
  __syncthreads();
  if (tid == 0) {
    float l[NE];
#pragma unroll
    for (int e = 0; e < NE; ++e) l[e] = red[0][e] + red[1][e] + red[2][e] + red[3][e];
    float mx = l[0];
#pragma unroll
    for (int e = 1; e < NE; ++e) mx = fmaxf(mx, l[e]);
    float pr[NE]; float sum = 0.f;
#pragma unroll
    for (int e = 0; e < NE; ++e) { pr[e] = __expf(l[e] - mx); sum += pr[e]; }
    float inv = 1.f / sum;
#pragma unroll
    for (int e = 0; e < NE; ++e) pr[e] *= inv;
    int i0 = 0; float p0 = pr[0];
#pragma unroll
    for (int e = 1; e < NE; ++e) if (pr[e] > p0) { p0 = pr[e]; i0 = e; }
    int i1 = -1; float p1 = -1.f;
#pragma unroll
    for (int e = 0; e < NE; ++e) if (e != i0 && pr[e] > p1) { p1 = pr[e]; i1 = e; }
    float wsum = p0 + p1;
    tope[t * 2 + 0] = i0; topw[t * 2 + 0] = p0 / wsum;
    tope[t * 2 + 1] = i1; topw[t * 2 + 1] = p1 / wsum;
    atomicAdd(&counts[i0], 1);
    atomicAdd(&counts[i1], 1);
  }
}

__global__ void prefix_kernel(const int* __restrict__ counts, int* __restrict__ basep) {
  if (threadIdx.x == 0 && blockIdx.x == 0) {
    int acc = 0;
    for (int e = 0; e < NE; ++e) { basep[e] = acc; acc += counts[e]; }
  }
}

__global__ void fill_kernel(const int* __restrict__ tope, const float* __restrict__ topw,
                            const int* __restrict__ basep, int* __restrict__ fillp,
                            int* __restrict__ rowtok, float* __restrict__ roww,
                            int* __restrict__ rowof) {
  int t = blockIdx.x * blockDim.x + threadIdx.x;
  if (t >= TTOK) return;
#pragma unroll
  for (int s = 0; s < 2; ++s) {
    int e = tope[t * 2 + s];
    int r = basep[e] + atomicAdd(&fillp[e], 1);
    rowtok[r] = t;
    roww[r] = topw[t * 2 + s];
    rowof[t * 2 + s] = r;
  }
}

// =========== 256x256 / BK=64 / 8-wave counted-vmcnt GEMM (T2+T3+T4+T5) ======
// MODE 0: A rows gathered via rowtok (xb), C -> bf16 plain store.
// MODE 1: A rows contiguous (H), C * roww[row] -> f32 store.
template <int MODE, int K, int N>
__global__ __launch_bounds__(512, 2) void gemm8(
    const unsigned short* __restrict__ Asrc, const unsigned short* __restrict__ Bw,
    const int* __restrict__ rowtok, const float* __restrict__ roww,
    const int* __restrict__ counts, const int* __restrict__ basep,
    void* __restrict__ Out) {
  const int e = blockIdx.z;
  const int cnt = counts[e];
  const int m0 = blockIdx.y * BM;
  if (m0 >= cnt) return;
  const int n0 = blockIdx.x * BM;   // BN == BM == 256
  const int base_e = basep[e];

  __shared__ unsigned short As[2][BM * BK];   // 2 x 32 KiB
  __shared__ unsigned short Bs[2][BM * BK];   // 2 x 32 KiB

  const int tid = threadIdx.x;
  const int lane = tid & 63;
  const int w = tid >> 6;          // 0..7
  const int wm = w >> 2;           // 0..1  (M half)
  const int wn = w & 3;            // 0..3  (N quarter)

  // ---- staging geometry: issue s covers rows s*64 + w*8 .. +7, 64 cols ----
  const int lsub  = lane >> 3;     // row within 8-row group
  const int lslot = lane & 7;      // 16B slot within 128B row
  // inverse-swizzle on global source so a LINEAR gl_lds write + swizzled read
  // is consistent: physical slot lslot holds logical slot (lslot ^ (row&7)).
  const int swz_e = 8 * (lslot ^ lsub);   // element offset within 64-col row

  const unsigned short* pA[4];
  const unsigned short* pB[4];
#pragma unroll
  for (int s = 0; s < 4; ++s) {
    int rl = s * 64 + w * 8 + lsub;           // row in tile 0..255
    int ga = m0 + rl; if (ga > cnt - 1) ga = cnt - 1;
    if (MODE == 0) {
      int tok = rowtok[base_e + ga];
      pA[s] = Asrc + (size_t)tok * K + swz_e;
    } else {
      pA[s] = Asrc + (size_t)(base_e + ga) * K + swz_e;
    }
    pB[s] = Bw + ((size_t)e * N + n0 + s * 64 + w * 8 + lsub) * K + swz_e;
  }

#define STAGE(BB, T) do { \
    unsigned short* ab = &As[BB][0]; unsigned short* bb = &Bs[BB][0]; \
    _Pragma("unroll") \
    for (int s = 0; s < 4; ++s) { \
      gl_lds16(pA[s] + (T) * BK, ab + (s * 64 + w * 8) * BK); \
      gl_lds16(pB[s] + (T) * BK, bb + (s * 64 + w * 8) * BK); \
    } \
  } while (0)

  // ---- fragment geometry ----
  const int frow = lane & 15;
  const int klane = lane >> 4;     // 0..3

  f32x4 acc[8][4];
#pragma unroll
  for (int mf = 0; mf < 8; ++mf)
#pragma unroll
    for (int nf = 0; nf < 4; ++nf) acc[mf][nf] = (f32x4)0.f;

#define COMPUTE(BB) do { \
    const unsigned short* ab = &As[BB][0]; const unsigned short* bb = &Bs[BB][0]; \
    _Pragma("unroll") \
    for (int kk = 0; kk < 2; ++kk) { \
      const int kswz = (kk * 32 + klane * 8) ^ ((frow & 7) * 8); \
      s16x8 a[8], b[4]; \
      _Pragma("unroll") \
      for (int mf = 0; mf < 8; ++mf) \
        a[mf] = *(const s16x8*)&ab[(wm * 128 + mf * 16 + frow) * BK + kswz]; \
      _Pragma("unroll") \
      for (int nf = 0; nf < 4; ++nf) \
        b[nf] = *(const s16x8*)&bb[(wn * 64 + nf * 16 + frow) * BK + kswz]; \
      __builtin_amdgcn_s_setprio(1); \
      _Pragma("unroll") \
      for (int mf = 0; mf < 8; ++mf) \
        _Pragma("unroll") \
        for (int nf = 0; nf < 4; ++nf) \
          acc[mf][nf] = __builtin_amdgcn_mfma_f32_16x16x32_bf16(a[mf], b[nf], acc[mf][nf], 0, 0, 0); \
      __builtin_amdgcn_s_setprio(0); \
    } \
  } while (0)

  const int NT = K / BK;
  // prologue: stage tiles 0 and 1; wait tile0 (keep tile1's 8 in flight)
  STAGE(0, 0);
  STAGE(1, 1);
  asm volatile("s_waitcnt vmcnt(8)" ::: "memory");
  __builtin_amdgcn_s_barrier();

  for (int t = 0; t < NT; ++t) {
    COMPUTE(t & 1);
    asm volatile("" ::: "memory");
    __builtin_amdgcn_s_barrier();          // all waves done reading buf[t&1]
    if (t + 1 < NT) {
      if (t + 2 < NT) {
        STAGE(t & 1, t + 2);               // refill freed buffer
        asm volatile("s_waitcnt vmcnt(8)" ::: "memory");  // tile t+1 resident
      } else {
        asm volatile("s_waitcnt vmcnt(0)" ::: "memory");  // final tile (once)
      }
      __builtin_amdgcn_s_barrier();
    }
  }
#undef STAGE
#undef COMPUTE

  // ---- epilogue ----
#pragma unroll
  for (int mf = 0; mf < 8; ++mf) {
#pragma unroll
    for (int nf = 0; nf < 4; ++nf) {
      int col = n0 + wn * 64 + nf * 16 + frow;
#pragma unroll
      for (int j = 0; j < 4; ++j) {
        int rl = wm * 128 + mf * 16 + klane * 4 + j;
        int grow = m0 + rl;
        if (grow < cnt) {
          if (MODE == 0) {
            ((unsigned short*)Out)[(size_t)(base_e + grow) * N + col] = f2bf(acc[mf][nf][j]);
          } else {
            float wv = roww[base_e + grow];
            ((float*)Out)[(size_t)(base_e + grow) * N + col] = acc[mf][nf][j] * wv;
          }
        }
      }
    }
  }
}

// H = silu(h1) * h3, elementwise, in-place capable (out == h1)
__global__ __launch_bounds__(256) void swiglu_kernel(const unsigned short* __restrict__ h1,
                                                     const unsigned short* __restrict__ h3,
                                                     unsigned short* __restrict__ H, int n8) {
  int i = blockIdx.x * 256 + threadIdx.x;
  if (i >= n8) return;
  u16x8 v1 = *(const u16x8*)(h1 + (size_t)i * 8);
  u16x8 v3 = *(const u16x8*)(h3 + (size_t)i * 8);
  u16x8 o;
#pragma unroll
  for (int j = 0; j < 8; ++j) {
    float s = bf2f(v1[j]);
    float g = bf2f(v3[j]);
    o[j] = f2bf((s / (1.f + __expf(-s))) * g);
  }
  *(u16x8*)(H + (size_t)i * 8) = o;
}

// y[t,:] = R[row0(t),:] + R[row1(t),:]
__global__ __launch_bounds__(256) void combine_kernel(const float* __restrict__ R,
                                                      const int* __restrict__ rowof,
                                                      float* __restrict__ y) {
  int idx = blockIdx.x * 256 + threadIdx.x;
  int t = idx >> 9;                           // D/4 = 512
  int d4 = idx & 511;
  int r0 = rowof[t * 2], r1 = rowof[t * 2 + 1];
  f32x4 a = *(const f32x4*)(R + (size_t)r0 * DIM + d4 * 4);
  f32x4 b = *(const f32x4*)(R + (size_t)r1 * DIM + d4 * 4);
  *(f32x4*)(y + (size_t)t * DIM + d4 * 4) = a + b;
}

extern "C" void kernel_launch(void* const* d_in, const int* in_sizes, int n_in,
                              void* d_out, int out_size, void* d_ws, size_t ws_size,
                              hipStream_t stream) {
  const float* x      = (const float*)d_in[0];
  const float* gate_w = (const float*)d_in[1];
  const float* w1     = (const float*)d_in[2];
  const float* w2     = (const float*)d_in[3];
  const float* w3     = (const float*)d_in[4];
  float* y = (float*)d_out;

  char* ws = (char*)d_ws;
  const size_t MB = 1ull << 20;
  // control block
  int*   tope   = (int*)(ws);
  float* topw   = (float*)(ws + (32 << 10));
  int*   rowtok = (int*)(ws + (64 << 10));
  float* roww   = (float*)(ws + (96 << 10));
  int*   rowof  = (int*)(ws + (128 << 10));
  int*   counts = (int*)(ws + (160 << 10));
  int*   basep  = counts + 32;
  int*   fillp  = counts + 64;

  unsigned short* xb  = (unsigned short*)(ws + 1 * MB);    // 16 MB
  unsigned short* H1  = (unsigned short*)(ws + 17 * MB);   // 64 MB (h1, then H in-place)
  unsigned short* H3  = (unsigned short*)(ws + 81 * MB);   // 64 MB
  unsigned short* w1b = (unsigned short*)(ws + 145 * MB);  // 128 MB
  unsigned short* w3b = (unsigned short*)(ws + 273 * MB);  // 128 MB
  unsigned short* w2b = (unsigned short*)(ws + 401 * MB);  // 128 MB (end 529)
  float*          R   = (float*)(ws + 145 * MB);           // 64 MB, aliases dead w1b

  hipMemsetAsync(counts, 0, 512, stream);
  router_kernel<<<TTOK, 256, 0, stream>>>(x, gate_w, tope, topw, counts);
  prefix_kernel<<<1, 64, 0, stream>>>(counts, basep);
  fill_kernel<<<TTOK / 256, 256, 0, stream>>>(tope, topw, basep, fillp, rowtok, roww, rowof);

  const int nw8 = NE * FF * DIM / 8;
  const int nx8 = TTOK * DIM / 8;
  cvt_kernel<<<nw8 / 256, 256, 0, stream>>>(w1, w1b, nw8);
  cvt_kernel<<<nw8 / 256, 256, 0, stream>>>(w3, w3b, nw8);
  cvt_kernel<<<nw8 / 256, 256, 0, stream>>>(w2, w2b, nw8);
  cvt_kernel<<<nx8 / 256, 256, 0, stream>>>(x, xb, nx8);

  // h1 = Xe @ w1^T ; h3 = Xe @ w3^T   (M=routed rows, N=FF, K=DIM)
  gemm8<0, DIM, FF><<<dim3(FF / BM, 16, NE), 512, 0, stream>>>(
      xb, w1b, rowtok, roww, counts, basep, (void*)H1);
  gemm8<0, DIM, FF><<<dim3(FF / BM, 16, NE), 512, 0, stream>>>(
      xb, w3b, rowtok, roww, counts, basep, (void*)H3);
  swiglu_kernel<<<TROWS * FF / 8 / 256, 256, 0, stream>>>(H1, H3, H1, TROWS * FF / 8);
  // R = roww * (H @ w2^T)   (M=routed rows, N=DIM, K=FF); w1b dead -> R aliases it
  gemm8<1, FF, DIM><<<dim3(DIM / BM, 16, NE), 512, 0, stream>>>(
      H1, w2b, rowtok, roww, counts, basep, (void*)R);
  combine_kernel<<<TTOK * DIM / 4 / 256, 256, 0, stream>>>(R, rowof, y);
}